// Round 19
// baseline (130.068 us; speedup 1.0000x reference)
//
#include <hip/hip_runtime.h>

#define NN 50000
#define NE 800000
#define DD 64
#define BS 100          // nodes per bucket
#define NB 500          // buckets (NB*BS == NN)
#define ECAP 2048       // edge slots per bucket (mean 1600, sigma 40)
#define CHUNK 3200      // edges per partition block
#define NPB 250         // partition blocks (NPB*CHUNK == NE)
#define EPT (ECAP / 256)  // 8 edges per thread in bucket_sort
#define NGRID (NN / 16)   // 3125 blocks per layer
#define AMP 8             // layer-0 amplification (instrumentation round)

typedef __attribute__((ext_vector_type(8))) short short8;
typedef __attribute__((ext_vector_type(4))) float f32x4;

// ---------------- helpers ----------------

__device__ __forceinline__ unsigned bf16_rnd(float f) {
    unsigned u = __float_as_uint(f);
    return u + 0x7FFFu + ((u >> 16) & 1u);     // RNE, take high 16
}
__device__ __forceinline__ unsigned pack2(float lo, float hi) {
    return (bf16_rnd(lo) >> 16) | (bf16_rnd(hi) & 0xFFFF0000u);
}
__device__ __forceinline__ float blo(unsigned u) { return __uint_as_float(u << 16); }
__device__ __forceinline__ float bhi(unsigned u) { return __uint_as_float(u & 0xFFFF0000u); }

// h (f32) -> packed bf16; block 0 zeroes gpos; blocks 1,2 build W-fragments.
__global__ __launch_bounds__(256) void f32_to_bf16_zero_kernel(
        const float4* __restrict__ in4, uint4* __restrict__ out4,
        int* __restrict__ gpos, const float* __restrict__ Ws,
        uint4* __restrict__ wfrag) {
    if (blockIdx.x == 0) {
        for (int j = threadIdx.x; j < NB; j += 256) gpos[j] = 0;
    }
    if (blockIdx.x == 1 || blockIdx.x == 2) {
        int L = blockIdx.x - 1;
        const float* W = Ws + L * DD * DD;
        for (int e = threadIdx.x; e < 512; e += 256) {
            int w = e >> 7;
            int s = (e >> 6) & 1;
            int l = e & 63;
            int col = w * 16 + (l & 15);
            int k0 = 32 * s + 8 * (l >> 4);
            uint4 u;
            unsigned* up = (unsigned*)&u;
            #pragma unroll
            for (int uu = 0; uu < 4; ++uu) {
                float lo = W[(k0 + 2 * uu) * DD + col];
                float hi = W[(k0 + 2 * uu + 1) * DD + col];
                up[uu] = pack2(lo, hi);
            }
            wfrag[L * 512 + e] = u;
        }
    }
    int i = blockIdx.x * blockDim.x + threadIdx.x;
    if (i >= NN * DD / 8) return;
    float4 a = in4[2 * i], b = in4[2 * i + 1];
    uint4 o;
    o.x = pack2(a.x, a.y); o.y = pack2(a.z, a.w);
    o.z = pack2(b.x, b.y); o.w = pack2(b.z, b.w);
    out4[i] = o;
}

// ---------------- edge partition by dst bucket, 1024-thread blocks ---------
__global__ __launch_bounds__(1024) void partition_kernel(
        const int* __restrict__ src, const int* __restrict__ dst,
        const float* __restrict__ ew,
        int* __restrict__ gpos, uint2* __restrict__ ebuf) {
    __shared__ int hist[NB];
    __shared__ int base[NB];
    int t = threadIdx.x;
    int c0 = blockIdx.x * CHUNK;

    for (int j = t; j < NB; j += 1024) hist[j] = 0;
    __syncthreads();

    short rank[4];
    int   dcache[4];
    #pragma unroll
    for (int i = 0; i < 4; ++i) {
        int o = i * 1024 + t;
        if (o < CHUNK) {
            int d = dst[c0 + o];
            dcache[i] = d;
            rank[i] = (short)atomicAdd(&hist[d / BS], 1);
        }
    }
    __syncthreads();

    for (int j = t; j < NB; j += 1024) {
        int c = hist[j];
        base[j] = c ? atomicAdd(&gpos[j], c) : 0;
    }
    __syncthreads();

    #pragma unroll
    for (int i = 0; i < 4; ++i) {
        int o = i * 1024 + t;
        if (o < CHUNK) {
            int e = c0 + o;
            int d = dcache[i];
            int bkt = d / BS;
            int dl = d - bkt * BS;
            int pos = base[bkt] + (int)rank[i];
            if (pos < ECAP) {
                ebuf[(size_t)bkt * ECAP + pos] =
                    make_uint2((unsigned)src[e] | ((unsigned)dl << 16),
                               __float_as_uint(ew[e]));
            }
        }
    }
}

// ---------------- per-bucket counting sort + within-bucket degree sort -----
__global__ __launch_bounds__(256) void bucket_sort_kernel(
        const uint2* __restrict__ ebuf, const int* __restrict__ gpos,
        unsigned* __restrict__ sorted, int4* __restrict__ nodespan) {
    __shared__ int hist[BS];
    __shared__ int sc[BS];
    __shared__ int dh[128];
    __shared__ int dsc[128];
    int t = threadIdx.x;
    int b = blockIdx.x;
    int cnt = min(gpos[b], ECAP);
    const uint2* slab = ebuf + (size_t)b * ECAP;

    if (t < BS) hist[t] = 0;
    if (t < 128) dh[t] = 0;
    __syncthreads();

    unsigned pay[EPT];
    int dl[EPT], rk[EPT];
    #pragma unroll
    for (int i = 0; i < EPT; ++i) {
        int o = i * 256 + t;
        if (o < cnt) {
            uint2 q = slab[o];
            dl[i]  = (int)(q.x >> 16);
            pay[i] = (q.x & 0xFFFFu) | (bf16_rnd(__uint_as_float(q.y)) & 0xFFFF0000u);
            rk[i]  = atomicAdd(&hist[dl[i]], 1);
        }
    }
    __syncthreads();

    if (t < BS) sc[t] = hist[t];
    __syncthreads();
    #pragma unroll
    for (int off = 1; off < BS; off <<= 1) {
        int v = (t < BS && t >= off) ? sc[t - off] : 0;
        __syncthreads();
        if (t < BS) sc[t] += v;
        __syncthreads();
    }

    unsigned* oslab = sorted + (size_t)b * ECAP;
    #pragma unroll
    for (int i = 0; i < EPT; ++i) {
        int o = i * 256 + t;
        if (o < cnt) oslab[sc[dl[i]] - hist[dl[i]] + rk[i]] = pay[i];
    }

    // ---- degree sort of the BS nodes ----
    if (t < BS) atomicAdd(&dh[min(hist[t], 127)], 1);
    __syncthreads();
    if (t < 128) dsc[t] = dh[t];
    __syncthreads();
    #pragma unroll
    for (int off = 1; off < 128; off <<= 1) {
        int v = (t < 128 && t >= off) ? dsc[t - off] : 0;
        __syncthreads();
        if (t < 128) dsc[t] += v;
        __syncthreads();
    }
    if (t < 128) dh[t] = dsc[t] - dh[t];
    __syncthreads();
    if (t < BS) {
        int d = min(hist[t], 127);
        int p = atomicAdd(&dh[d], 1);
        nodespan[b * BS + p] =
            make_int4(b * ECAP + sc[t] - hist[t], hist[t], b * BS + t, 0);
    }
}

// ---------------- fused gather(bf16) + MFMA dense + relu -------------------
// copy>0 blocks redo identical work into outp2 (amplification for profiling).
template<bool WRITE_BF16>
__global__ __launch_bounds__(256) void gcn_layer_kernel(
        const uint2* __restrict__ hb,
        const unsigned* __restrict__ sorted,
        const int4* __restrict__ nodespan,
        const uint4* __restrict__ wfrag,
        const float* __restrict__ bvec,
        void* __restrict__ outp,
        void* __restrict__ outp2) {
    __shared__ unsigned Abf[16 * 36];
    __shared__ float Dls[16 * 68];
    __shared__ int nid[16];
    int t = threadIdx.x;

    int copy = blockIdx.x / NGRID;
    int vb   = blockIdx.x - copy * NGRID;
    void* op = (copy == 0) ? outp : outp2;

    int g = t >> 4;
    int lane = t & 15;
    int v = vb * 16 + g;

    int4 sp = nodespan[v];
    if (lane == 0) nid[g] = sp.z;
    const unsigned* row = sorted + sp.x;
    int deg = sp.y;

    float4 a0 = make_float4(0.f, 0.f, 0.f, 0.f);
    float4 a1 = make_float4(0.f, 0.f, 0.f, 0.f);
    float4 a2 = make_float4(0.f, 0.f, 0.f, 0.f);
    float4 a3 = make_float4(0.f, 0.f, 0.f, 0.f);
    unsigned ul = (unsigned)lane;
    for (int k0 = 0; k0 < deg; k0 += 16) {
        int kk = k0 + lane;
        unsigned q = (kk < deg) ? row[kk] : 0u;
        int lim = min(16, deg - k0);
        int j = 0;
        for (; j + 4 <= lim; j += 4) {
            unsigned q0 = (unsigned)__shfl((int)q, j + 0, 16);
            unsigned q1 = (unsigned)__shfl((int)q, j + 1, 16);
            unsigned q2 = (unsigned)__shfl((int)q, j + 2, 16);
            unsigned q3 = (unsigned)__shfl((int)q, j + 3, 16);
            uint2 r0 = hb[(q0 & 0xFFFFu) * 16u + ul];
            uint2 r1 = hb[(q1 & 0xFFFFu) * 16u + ul];
            uint2 r2 = hb[(q2 & 0xFFFFu) * 16u + ul];
            uint2 r3 = hb[(q3 & 0xFFFFu) * 16u + ul];
            float w0 = bhi(q0), w1 = bhi(q1), w2 = bhi(q2), w3 = bhi(q3);
            a0.x += w0 * blo(r0.x); a0.y += w0 * bhi(r0.x);
            a0.z += w0 * blo(r0.y); a0.w += w0 * bhi(r0.y);
            a1.x += w1 * blo(r1.x); a1.y += w1 * bhi(r1.x);
            a1.z += w1 * blo(r1.y); a1.w += w1 * bhi(r1.y);
            a2.x += w2 * blo(r2.x); a2.y += w2 * bhi(r2.x);
            a2.z += w2 * blo(r2.y); a2.w += w2 * bhi(r2.y);
            a3.x += w3 * blo(r3.x); a3.y += w3 * bhi(r3.x);
            a3.z += w3 * blo(r3.y); a3.w += w3 * bhi(r3.y);
        }
        for (; j < lim; ++j) {
            unsigned q0 = (unsigned)__shfl((int)q, j, 16);
            float w0 = bhi(q0);
            uint2 r0 = hb[(q0 & 0xFFFFu) * 16u + ul];
            a0.x += w0 * blo(r0.x); a0.y += w0 * bhi(r0.x);
            a0.z += w0 * blo(r0.y); a0.w += w0 * bhi(r0.y);
        }
    }
    a0.x += a1.x + a2.x + a3.x;
    a0.y += a1.y + a2.y + a3.y;
    a0.z += a1.z + a2.z + a3.z;
    a0.w += a1.w + a2.w + a3.w;

    Abf[g * 36 + 2 * lane]     = pack2(a0.x, a0.y);
    Abf[g * 36 + 2 * lane + 1] = pack2(a0.z, a0.w);
    __syncthreads();

    // ---- MFMA: wave w -> cols 16w..16w+15, K=64 in 2 steps ----
    {
        int w = t >> 6;
        int l = t & 63;
        const uint4* arow = (const uint4*)(&Abf[(l & 15) * 36]);
        uint4 au0 = arow[l >> 4];
        uint4 au1 = arow[4 + (l >> 4)];
        uint4 bu0 = wfrag[(w * 2 + 0) * 64 + l];
        uint4 bu1 = wfrag[(w * 2 + 1) * 64 + l];
        f32x4 d = {0.f, 0.f, 0.f, 0.f};
        d = __builtin_amdgcn_mfma_f32_16x16x32_bf16(
                *(const short8*)&au0, *(const short8*)&bu0, d, 0, 0, 0);
        d = __builtin_amdgcn_mfma_f32_16x16x32_bf16(
                *(const short8*)&au1, *(const short8*)&bu1, d, 0, 0, 0);
        #pragma unroll
        for (int r = 0; r < 4; ++r)
            Dls[((l >> 4) * 4 + r) * 68 + w * 16 + (l & 15)] = d[r];
    }
    __syncthreads();

    float4 bias = reinterpret_cast<const float4*>(bvec)[lane];
    float4 dv = *reinterpret_cast<const float4*>(&Dls[g * 68 + lane * 4]);
    float4 o;
    o.x = fmaxf(dv.x + bias.x, 0.f);
    o.y = fmaxf(dv.y + bias.y, 0.f);
    o.z = fmaxf(dv.z + bias.z, 0.f);
    o.w = fmaxf(dv.w + bias.w, 0.f);
    int node = nid[g];
    if (WRITE_BF16) {
        reinterpret_cast<uint2*>(op)[(size_t)node * 16 + lane] =
            make_uint2(pack2(o.x, o.y), pack2(o.z, o.w));
    } else {
        reinterpret_cast<float4*>(op)[(size_t)node * 16 + lane] = o;
    }
}

extern "C" void kernel_launch(void* const* d_in, const int* in_sizes, int n_in,
                              void* d_out, int out_size, void* d_ws, size_t ws_size,
                              hipStream_t stream) {
    const float* h   = (const float*)d_in[0];
    const float* Ws  = (const float*)d_in[1];   // [2][64][64]
    const float* bs  = (const float*)d_in[2];   // [2][64]
    const float* ew  = (const float*)d_in[3];
    const int*   src = (const int*)d_in[4];
    const int*   dst = (const int*)d_in[5];
    float* out = (float*)d_out;
    char* ws = (char*)d_ws;

    // ws layout (~31 MB):
    //   gpos:     [0, 2 KB)
    //   ebuf:     [64 KB, 8.06 MB)      [dead after sort]
    //   h1:       [1 MB, 7.4 MB)        bf16, aliases dead ebuf region
    //   sorted:   [9 MB, 13 MB)
    //   wfrag:    [13 MB, 13 MB+16 KB)
    //   nodespan: [13.25 MB, 14.05 MB)
    //   h_bf:     [14.5 MB, 20.9 MB)
    //   h2:       [24 MB, 30.4 MB)      scratch for amplified copies
    int*      gpos     = (int*)(ws);
    uint2*    ebuf     = (uint2*)(ws + 64 * 1024);
    void*     h1       = (void*)(ws + 1u * 1024 * 1024);
    unsigned* sorted   = (unsigned*)(ws + 9u * 1024 * 1024);
    uint4*    wfrag    = (uint4*)(ws + 13u * 1024 * 1024);
    int4*     nodespan = (int4*)(ws + 13u * 1024 * 1024 + 256 * 1024);
    uint2*    h_bf     = (uint2*)(ws + 14u * 1024 * 1024 + 512 * 1024);
    void*     h2       = (void*)(ws + 24u * 1024 * 1024);

    dim3 blk(256);

    f32_to_bf16_zero_kernel<<<(NN * DD / 8 + 255) / 256, blk, 0, stream>>>(
        (const float4*)h, (uint4*)h_bf, gpos, Ws, wfrag);
    partition_kernel<<<NPB, dim3(1024), 0, stream>>>(src, dst, ew, gpos, ebuf);
    bucket_sort_kernel<<<NB, blk, 0, stream>>>(ebuf, gpos, sorted, nodespan);

    // Layer 0, AMPLIFIED 8x for profiling: copy 0 -> h1 (real), copies 1-7 -> h2.
    gcn_layer_kernel<true><<<AMP * NGRID, blk, 0, stream>>>(
        h_bf, sorted, nodespan, wfrag, bs, h1, h2);
    // Layer 1: h1 -> out (f32)
    gcn_layer_kernel<false><<<NGRID, blk, 0, stream>>>(
        (const uint2*)h1, sorted, nodespan, wfrag + 512, bs + DD, (void*)out, h2);
}

// Round 20
// 64.724 us; speedup vs baseline: 2.0096x; 2.0096x over previous
//
#include <hip/hip_runtime.h>
#include <hip/hip_fp16.h>

#define NN 50000
#define NE 800000
#define DD 64
#define BS 100          // nodes per bucket
#define NB 500          // buckets (NB*BS == NN)
#define ECAP 2048       // edge slots per bucket (mean 1600, sigma 40)
#define CHUNK 3200      // edges per partition block
#define NPB 250         // partition blocks (NPB*CHUNK == NE)
#define EPT (ECAP / 256)  // 8 edges per thread in bucket_sort
#define NGRID (NN / 16)   // 3125 blocks per layer

typedef __attribute__((ext_vector_type(8))) short short8;
typedef __attribute__((ext_vector_type(4))) float f32x4;

// ---------------- helpers ----------------

__device__ __forceinline__ unsigned packh2(float lo, float hi) {
    __half2 h = __floats2half2_rn(lo, hi);
    return *reinterpret_cast<unsigned*>(&h);
}

// h (f32) -> packed fp16; block 0 zeroes gpos; blocks 1,2 build W-fragments (fp16).
__global__ __launch_bounds__(256) void f32_to_f16_zero_kernel(
        const float4* __restrict__ in4, uint4* __restrict__ out4,
        int* __restrict__ gpos, const float* __restrict__ Ws,
        uint4* __restrict__ wfrag) {
    if (blockIdx.x == 0) {
        for (int j = threadIdx.x; j < NB; j += 256) gpos[j] = 0;
    }
    if (blockIdx.x == 1 || blockIdx.x == 2) {
        int L = blockIdx.x - 1;
        const float* W = Ws + L * DD * DD;
        for (int e = threadIdx.x; e < 512; e += 256) {
            int w = e >> 7;         // col tile 0..3
            int s = (e >> 6) & 1;   // k step 0..1
            int l = e & 63;         // lane
            int col = w * 16 + (l & 15);
            int k0 = 32 * s + 8 * (l >> 4);
            uint4 u;
            unsigned* up = (unsigned*)&u;
            #pragma unroll
            for (int uu = 0; uu < 4; ++uu) {
                float lo = W[(k0 + 2 * uu) * DD + col];
                float hi = W[(k0 + 2 * uu + 1) * DD + col];
                up[uu] = packh2(lo, hi);
            }
            wfrag[L * 512 + e] = u;
        }
    }
    int i = blockIdx.x * blockDim.x + threadIdx.x;
    if (i >= NN * DD / 8) return;
    float4 a = in4[2 * i], b = in4[2 * i + 1];
    uint4 o;
    o.x = packh2(a.x, a.y); o.y = packh2(a.z, a.w);
    o.z = packh2(b.x, b.y); o.w = packh2(b.z, b.w);
    out4[i] = o;
}

// ---------------- edge partition by dst bucket, 1024-thread blocks ---------
__global__ __launch_bounds__(1024) void partition_kernel(
        const int* __restrict__ src, const int* __restrict__ dst,
        const float* __restrict__ ew,
        int* __restrict__ gpos, uint2* __restrict__ ebuf) {
    __shared__ int hist[NB];
    __shared__ int base[NB];
    int t = threadIdx.x;
    int c0 = blockIdx.x * CHUNK;

    for (int j = t; j < NB; j += 1024) hist[j] = 0;
    __syncthreads();

    short rank[4];
    int   dcache[4];
    #pragma unroll
    for (int i = 0; i < 4; ++i) {
        int o = i * 1024 + t;
        if (o < CHUNK) {
            int d = dst[c0 + o];
            dcache[i] = d;
            rank[i] = (short)atomicAdd(&hist[d / BS], 1);
        }
    }
    __syncthreads();

    for (int j = t; j < NB; j += 1024) {
        int c = hist[j];
        base[j] = c ? atomicAdd(&gpos[j], c) : 0;
    }
    __syncthreads();

    #pragma unroll
    for (int i = 0; i < 4; ++i) {
        int o = i * 1024 + t;
        if (o < CHUNK) {
            int e = c0 + o;
            int d = dcache[i];
            int bkt = d / BS;
            int dl = d - bkt * BS;
            int pos = base[bkt] + (int)rank[i];
            if (pos < ECAP) {
                ebuf[(size_t)bkt * ECAP + pos] =
                    make_uint2((unsigned)src[e] | ((unsigned)dl << 16),
                               __float_as_uint(ew[e]));
            }
        }
    }
}

// ---------------- per-bucket counting sort + within-bucket degree sort -----
// Payload: src (low 16) | fp16 weight (high 16). Nodespan degree-sorted.
__global__ __launch_bounds__(256) void bucket_sort_kernel(
        const uint2* __restrict__ ebuf, const int* __restrict__ gpos,
        unsigned* __restrict__ sorted, int4* __restrict__ nodespan) {
    __shared__ int hist[BS];
    __shared__ int sc[BS];
    __shared__ int dh[128];
    __shared__ int dsc[128];
    int t = threadIdx.x;
    int b = blockIdx.x;
    int cnt = min(gpos[b], ECAP);
    const uint2* slab = ebuf + (size_t)b * ECAP;

    if (t < BS) hist[t] = 0;
    if (t < 128) dh[t] = 0;
    __syncthreads();

    unsigned pay[EPT];
    int dl[EPT], rk[EPT];
    #pragma unroll
    for (int i = 0; i < EPT; ++i) {
        int o = i * 256 + t;
        if (o < cnt) {
            uint2 q = slab[o];
            dl[i]  = (int)(q.x >> 16);
            unsigned w16 = (unsigned)__half_as_ushort(
                __float2half(__uint_as_float(q.y)));
            pay[i] = (q.x & 0xFFFFu) | (w16 << 16);
            rk[i]  = atomicAdd(&hist[dl[i]], 1);
        }
    }
    __syncthreads();

    if (t < BS) sc[t] = hist[t];
    __syncthreads();
    #pragma unroll
    for (int off = 1; off < BS; off <<= 1) {
        int v = (t < BS && t >= off) ? sc[t - off] : 0;
        __syncthreads();
        if (t < BS) sc[t] += v;
        __syncthreads();
    }

    unsigned* oslab = sorted + (size_t)b * ECAP;
    #pragma unroll
    for (int i = 0; i < EPT; ++i) {
        int o = i * 256 + t;
        if (o < cnt) oslab[sc[dl[i]] - hist[dl[i]] + rk[i]] = pay[i];
    }

    // ---- degree sort of the BS nodes ----
    if (t < BS) atomicAdd(&dh[min(hist[t], 127)], 1);
    __syncthreads();
    if (t < 128) dsc[t] = dh[t];
    __syncthreads();
    #pragma unroll
    for (int off = 1; off < 128; off <<= 1) {
        int v = (t < 128 && t >= off) ? dsc[t - off] : 0;
        __syncthreads();
        if (t < 128) dsc[t] += v;
        __syncthreads();
    }
    if (t < 128) dh[t] = dsc[t] - dh[t];
    __syncthreads();
    if (t < BS) {
        int d = min(hist[t], 127);
        int p = atomicAdd(&dh[d], 1);
        nodespan[b * BS + p] =
            make_int4(b * ECAP + sc[t] - hist[t], hist[t], b * BS + t, 0);
    }
}

// ---------------- fused gather(fp16 pk_fma) + MFMA(f16) dense + relu -------
// 16 lanes/node, uint2 row slice = 4 fp16 dims. Per edge: splat fp16 w to
// half2, 2x v_pk_fma_f16 -> ~8 VALU/edge (was ~13 with bf16 unpack).
// Accumulated half2 pairs feed the f16 MFMA A-fragment directly.
template<bool WRITE_F16>
__global__ __launch_bounds__(256) void gcn_layer_kernel(
        const uint2* __restrict__ hh,         // [NN*16] fp16-packed rows
        const unsigned* __restrict__ sorted,
        const int4* __restrict__ nodespan,    // {start, deg, node, 0}
        const uint4* __restrict__ wfrag,      // fp16 W-fragments
        const float* __restrict__ bvec,
        void* __restrict__ outp) {
    __shared__ unsigned Ahf[16 * 36];         // [row][64 fp16 + pad]
    __shared__ float Dls[16 * 68];
    __shared__ int nid[16];
    int t = threadIdx.x;
    int g = t >> 4;
    int lane = t & 15;
    int v = blockIdx.x * 16 + g;

    int4 sp = nodespan[v];
    if (lane == 0) nid[g] = sp.z;
    const unsigned* row = sorted + sp.x;
    int deg = sp.y;

    __half2 z = __floats2half2_rn(0.f, 0.f);
    __half2 a0 = z, a1 = z, b0 = z, b1 = z, c0 = z, c1 = z, d0 = z, d1 = z;
    unsigned ul = (unsigned)lane;
    for (int k0 = 0; k0 < deg; k0 += 16) {
        int kk = k0 + lane;
        unsigned q = (kk < deg) ? row[kk] : 0u;
        int lim = min(16, deg - k0);
        int j = 0;
        for (; j + 4 <= lim; j += 4) {
            unsigned q0 = (unsigned)__shfl((int)q, j + 0, 16);
            unsigned q1 = (unsigned)__shfl((int)q, j + 1, 16);
            unsigned q2 = (unsigned)__shfl((int)q, j + 2, 16);
            unsigned q3 = (unsigned)__shfl((int)q, j + 3, 16);
            uint2 r0 = hh[(q0 & 0xFFFFu) * 16u + ul];
            uint2 r1 = hh[(q1 & 0xFFFFu) * 16u + ul];
            uint2 r2 = hh[(q2 & 0xFFFFu) * 16u + ul];
            uint2 r3 = hh[(q3 & 0xFFFFu) * 16u + ul];
            __half2 w0 = __half2half2(__ushort_as_half((unsigned short)(q0 >> 16)));
            __half2 w1 = __half2half2(__ushort_as_half((unsigned short)(q1 >> 16)));
            __half2 w2 = __half2half2(__ushort_as_half((unsigned short)(q2 >> 16)));
            __half2 w3 = __half2half2(__ushort_as_half((unsigned short)(q3 >> 16)));
            a0 = __hfma2(w0, *(const __half2*)&r0.x, a0);
            a1 = __hfma2(w0, *(const __half2*)&r0.y, a1);
            b0 = __hfma2(w1, *(const __half2*)&r1.x, b0);
            b1 = __hfma2(w1, *(const __half2*)&r1.y, b1);
            c0 = __hfma2(w2, *(const __half2*)&r2.x, c0);
            c1 = __hfma2(w2, *(const __half2*)&r2.y, c1);
            d0 = __hfma2(w3, *(const __half2*)&r3.x, d0);
            d1 = __hfma2(w3, *(const __half2*)&r3.y, d1);
        }
        for (; j < lim; ++j) {
            unsigned q0 = (unsigned)__shfl((int)q, j, 16);
            uint2 r0 = hh[(q0 & 0xFFFFu) * 16u + ul];
            __half2 w0 = __half2half2(__ushort_as_half((unsigned short)(q0 >> 16)));
            a0 = __hfma2(w0, *(const __half2*)&r0.x, a0);
            a1 = __hfma2(w0, *(const __half2*)&r0.y, a1);
        }
    }
    a0 = __hadd2(__hadd2(a0, b0), __hadd2(c0, d0));
    a1 = __hadd2(__hadd2(a1, b1), __hadd2(c1, d1));

    Ahf[g * 36 + 2 * lane]     = *reinterpret_cast<unsigned*>(&a0);
    Ahf[g * 36 + 2 * lane + 1] = *reinterpret_cast<unsigned*>(&a1);
    __syncthreads();

    // ---- MFMA f16: wave w -> cols 16w..16w+15, K=64 in 2 steps ----
    {
        int w = t >> 6;
        int l = t & 63;
        const uint4* arow = (const uint4*)(&Ahf[(l & 15) * 36]);
        uint4 au0 = arow[l >> 4];
        uint4 au1 = arow[4 + (l >> 4)];
        uint4 bu0 = wfrag[(w * 2 + 0) * 64 + l];
        uint4 bu1 = wfrag[(w * 2 + 1) * 64 + l];
        f32x4 d = {0.f, 0.f, 0.f, 0.f};
        d = __builtin_amdgcn_mfma_f32_16x16x32_f16(
                *(const short8*)&au0, *(const short8*)&bu0, d, 0, 0, 0);
        d = __builtin_amdgcn_mfma_f32_16x16x32_f16(
                *(const short8*)&au1, *(const short8*)&bu1, d, 0, 0, 0);
        #pragma unroll
        for (int r = 0; r < 4; ++r)
            Dls[((l >> 4) * 4 + r) * 68 + w * 16 + (l & 15)] = d[r];
    }
    __syncthreads();

    float4 bias = reinterpret_cast<const float4*>(bvec)[lane];
    float4 dv = *reinterpret_cast<const float4*>(&Dls[g * 68 + lane * 4]);
    float4 o;
    o.x = fmaxf(dv.x + bias.x, 0.f);
    o.y = fmaxf(dv.y + bias.y, 0.f);
    o.z = fmaxf(dv.z + bias.z, 0.f);
    o.w = fmaxf(dv.w + bias.w, 0.f);
    int node = nid[g];
    if (WRITE_F16) {
        reinterpret_cast<uint2*>(outp)[(size_t)node * 16 + lane] =
            make_uint2(packh2(o.x, o.y), packh2(o.z, o.w));
    } else {
        reinterpret_cast<float4*>(outp)[(size_t)node * 16 + lane] = o;
    }
}

extern "C" void kernel_launch(void* const* d_in, const int* in_sizes, int n_in,
                              void* d_out, int out_size, void* d_ws, size_t ws_size,
                              hipStream_t stream) {
    const float* h   = (const float*)d_in[0];
    const float* Ws  = (const float*)d_in[1];   // [2][64][64]
    const float* bs  = (const float*)d_in[2];   // [2][64]
    const float* ew  = (const float*)d_in[3];
    const int*   src = (const int*)d_in[4];
    const int*   dst = (const int*)d_in[5];
    float* out = (float*)d_out;
    char* ws = (char*)d_ws;

    // ws layout (~21 MB):
    //   gpos:     [0, 2 KB)
    //   ebuf:     [64 KB, 8.06 MB)      [dead after sort]
    //   h1:       [1 MB, 7.4 MB)        fp16, aliases dead ebuf region
    //   sorted:   [9 MB, 13 MB)
    //   wfrag:    [13 MB, 13 MB+16 KB)
    //   nodespan: [13.25 MB, 14.05 MB)
    //   h_hf:     [14.5 MB, 20.9 MB)    NN*DD fp16
    int*      gpos     = (int*)(ws);
    uint2*    ebuf     = (uint2*)(ws + 64 * 1024);
    void*     h1       = (void*)(ws + 1u * 1024 * 1024);
    unsigned* sorted   = (unsigned*)(ws + 9u * 1024 * 1024);
    uint4*    wfrag    = (uint4*)(ws + 13u * 1024 * 1024);
    int4*     nodespan = (int4*)(ws + 13u * 1024 * 1024 + 256 * 1024);
    uint2*    h_hf     = (uint2*)(ws + 14u * 1024 * 1024 + 512 * 1024);

    dim3 blk(256);

    f32_to_f16_zero_kernel<<<(NN * DD / 8 + 255) / 256, blk, 0, stream>>>(
        (const float4*)h, (uint4*)h_hf, gpos, Ws, wfrag);
    partition_kernel<<<NPB, dim3(1024), 0, stream>>>(src, dst, ew, gpos, ebuf);
    bucket_sort_kernel<<<NB, blk, 0, stream>>>(ebuf, gpos, sorted, nodespan);

    // Layer 0: h_hf -> h1 (fp16). h1 aliases ebuf, dead after sort.
    gcn_layer_kernel<true><<<NGRID, blk, 0, stream>>>(
        h_hf, sorted, nodespan, wfrag, bs, h1);
    // Layer 1: h1 -> out (f32)
    gcn_layer_kernel<false><<<NGRID, blk, 0, stream>>>(
        (const uint2*)h1, sorted, nodespan, wfrag + 512, bs + DD, (void*)out);
}